// Round 12
// baseline (473.306 us; speedup 1.0000x reference)
//
#include <hip/hip_runtime.h>

typedef __bf16 bf16;
typedef __bf16 bf16x4 __attribute__((ext_vector_type(4)));
typedef __bf16 bf16x8 __attribute__((ext_vector_type(8)));
typedef float f32x4 __attribute__((ext_vector_type(4)));

#define GLP16(gp, lp) __builtin_amdgcn_global_load_lds( \
    (const __attribute__((address_space(1))) void*)(gp), \
    (__attribute__((address_space(3))) void*)(lp), 16, 0, 0)

__device__ __forceinline__ f32x4 mfma16(bf16x8 a, bf16x8 b, f32x4 c) {
    return __builtin_amdgcn_mfma_f32_16x16x32_bf16(a, b, c, 0, 0, 0);
}

// ---------------- RMSNorm: fp32 in -> bf16 out, row = 2048 ----------------
__global__ __launch_bounds__(256) void k_rmsnorm(const float* __restrict__ x,
        const float* __restrict__ w, bf16* __restrict__ out) {
    const int H = 2048;
    size_t row = blockIdx.x;
    const float* xr = x + row * H;
    int base = threadIdx.x * 8;
    float4 a = *(const float4*)(xr + base);
    float4 b = *(const float4*)(xr + base + 4);
    float ss = a.x*a.x + a.y*a.y + a.z*a.z + a.w*a.w
             + b.x*b.x + b.y*b.y + b.z*b.z + b.w*b.w;
#pragma unroll
    for (int m = 32; m > 0; m >>= 1) ss += __shfl_xor(ss, m);
    __shared__ float red[4];
    if ((threadIdx.x & 63) == 0) red[threadIdx.x >> 6] = ss;
    __syncthreads();
    float tot = red[0] + red[1] + red[2] + red[3];
    float rs = rsqrtf(tot * (1.0f / H) + 1e-5f);
    float4 wa = *(const float4*)(w + base);
    float4 wb = *(const float4*)(w + base + 4);
    bf16x8 ov;
    ov[0] = (bf16)(a.x * rs * wa.x); ov[1] = (bf16)(a.y * rs * wa.y);
    ov[2] = (bf16)(a.z * rs * wa.z); ov[3] = (bf16)(a.w * rs * wa.w);
    ov[4] = (bf16)(b.x * rs * wb.x); ov[5] = (bf16)(b.y * rs * wb.y);
    ov[6] = (bf16)(b.z * rs * wb.z); ov[7] = (bf16)(b.w * rs * wb.w);
    *(bf16x8*)(out + row * H + base) = ov;
}

// ------- convT v2: W (K x N fp32) -> Wt (N*rmul+roff rows, K bf16 cols) ---
__global__ __launch_bounds__(256) void k_convT(const float* __restrict__ W,
        bf16* __restrict__ Wt, int K, int N, int rmul, int roff) {
    __shared__ float t[64][65];
    int k0 = blockIdx.x * 64, n0 = blockIdx.y * 64;
    int tid = threadIdx.x;
#pragma unroll
    for (int it = 0; it < 4; it++) {
        int idx = it * 256 + tid;
        int r = idx >> 4, c = (idx & 15) * 4;
        float4 v = *(const float4*)(W + (size_t)(k0 + r) * N + n0 + c);
        t[r][c] = v.x; t[r][c + 1] = v.y; t[r][c + 2] = v.z; t[r][c + 3] = v.w;
    }
    __syncthreads();
#pragma unroll
    for (int it = 0; it < 4; it++) {
        int idx = it * 256 + tid;
        int n = idx >> 4, kc = (idx & 15) * 4;
        bf16x4 o;
#pragma unroll
        for (int j = 0; j < 4; j++) o[j] = (bf16)t[kc + j][n];
        *(bf16x4*)(Wt + ((size_t)(n0 + n) * rmul + roff) * K + k0 + kc) = o;
    }
}

// ------- bf16 transpose: in (R x C) -> out (C x R) ------------------------
__global__ __launch_bounds__(256) void k_transpose(const bf16* __restrict__ in,
        bf16* __restrict__ out, int R, int C) {
    __shared__ bf16 t[32][33];
    int r0 = blockIdx.x * 32, c0 = blockIdx.y * 32;
    int tx = threadIdx.x & 31, ty = threadIdx.x >> 5;
#pragma unroll
    for (int i = 0; i < 4; i++)
        t[ty + i * 8][tx] = in[(size_t)(r0 + ty + i * 8) * C + c0 + tx];
    __syncthreads();
#pragma unroll
    for (int i = 0; i < 4; i++)
        out[(size_t)(c0 + ty + i * 8) * R + r0 + tx] = t[tx][ty + i * 8];
}

// ---------------- GEMM v9: 256x128 tile, BK=32, 2 blocks/CU ---------------
// 8 waves (4M x 2N), per-wave 64x64 -> acc 64 regs; __launch_bounds__(512,4)
// caps at 128 regs/wave so TWO blocks co-reside per CU (occupancy mechanism:
// offset phases of the two blocks cover each other's barrier/LDS stalls).
// LDS 48KB/block: A dbuf 2x16KB @0, B dbuf 2x8KB @32KB. 64B rows packed 2
// per 128B line, XOR-swizzled (line&7)<<4 (2-way = free); GLP dest linear,
// source pre-swizzled (rule 21).
// Per K-step s (buf s&1): P1 {8 ds_read + 8 MFMA + lgkmcnt(0) + barrier};
// P2 {stage tile s+2 (3 GLP, buffer freed by P1 barrier) + 8 MFMA +
// vmcnt(3) + barrier}. Stage->consume = 2 phases (>= HBM latency at 2
// blocks/CU). vmcnt(3) = keep s+2's stages in flight, enforce s+1's.
// EPI: 4 = fused gate/up silu (even cols = gate), 5 = bf16 partial (split-K)
template<int EPI>
__global__ __launch_bounds__(512, 4) void k_gemm9(const bf16* __restrict__ A,
        const bf16* __restrict__ Bt, void* __restrict__ outp,
        const void* __restrict__ aux, int M, int N, int K, int ksplit) {
    extern __shared__ char lds[];
    const int tid = threadIdx.x, wave = tid >> 6, lane = tid & 63;
    const int lr = lane & 15, kg = lane >> 4;
    const int wm = wave >> 1, wn = wave & 1;
    const int bn = blockIdx.x, bm = blockIdx.y, split = blockIdx.z;
    const int row0 = bm * 256, col0 = bn * 128;
    const int kbeg = split * ksplit;
    const int NT = ksplit >> 5;          // K-steps of 32
    const size_t K2 = (size_t)K * 2;

    // staging: linear dest byte d -> pre-swizzled global source offset
    int soffA[2], soffB;
    {
#pragma unroll
        for (int s = 0; s < 2; s++) {
            int d = wave * 2048 + s * 1024 + lane * 16;
            int line = d >> 7, w = d & 127;
            int wp = w ^ ((line & 7) << 4);
            soffA[s] = (line * 2 + (wp >> 6)) * (int)K2 + (wp & 63);
        }
        int d = wave * 1024 + lane * 16;
        int line = d >> 7, w = d & 127;
        int wp = w ^ ((line & 7) << 4);
        soffB = (line * 2 + (wp >> 6)) * (int)K2 + (wp & 63);
    }
    const char* Ab = (const char*)A + ((size_t)row0 * K + kbeg) * 2;
    const char* Bb = (const char*)Bt + ((size_t)col0 * K + kbeg) * 2;

    auto stage = [&](int t) {
        const char* sa = Ab + (size_t)t * 64;
        char* da = lds + (t & 1) * 16384 + wave * 2048;
        GLP16(sa + soffA[0], da);
        GLP16(sa + soffA[1], da + 1024);
        const char* sb = Bb + (size_t)t * 64;
        char* db = lds + 32768 + (t & 1) * 8192 + wave * 1024;
        GLP16(sb + soffB, db);
    };

    f32x4 acc[4][4];
#pragma unroll
    for (int m = 0; m < 4; m++)
#pragma unroll
        for (int n = 0; n < 4; n++) acc[m][n] = (f32x4){0, 0, 0, 0};

    bf16x8 a[4], b[4];
    auto rdA = [&](const char* base) {
#pragma unroll
        for (int mi = 0; mi < 4; mi++) {
            int r = wm * 64 + mi * 16 + lr;
            int line = r >> 1;
            int off = (((r & 1) << 6) + (kg << 4)) ^ ((line & 7) << 4);
            a[mi] = *(const bf16x8*)(base + line * 128 + off);
        }
    };
    auto rdB = [&](const char* base) {
#pragma unroll
        for (int nj = 0; nj < 4; nj++) {
            int r = wn * 64 + nj * 16 + lr;
            int line = r >> 1;
            int off = (((r & 1) << 6) + (kg << 4)) ^ ((line & 7) << 4);
            b[nj] = *(const bf16x8*)(base + line * 128 + off);
        }
    };
    auto mm2 = [&](int njb) {
#pragma unroll
        for (int mi = 0; mi < 4; mi++)
#pragma unroll
            for (int dn = 0; dn < 2; dn++)
                acc[mi][njb + dn] = mfma16(a[mi], b[njb + dn], acc[mi][njb + dn]);
    };

#define PBAR do { asm volatile("" ::: "memory"); \
                  __builtin_amdgcn_s_barrier(); \
                  asm volatile("" ::: "memory"); } while (0)

    // prologue: stage steps 0,1; wait step 0 (leave step 1's 3 in flight)
    stage(0); stage(1);
    asm volatile("s_waitcnt vmcnt(3)" ::: "memory");
    PBAR;

    for (int s = 0; s < NT; ++s) {
        const char* Ac = lds + (s & 1) * 16384;
        const char* Bc = lds + 32768 + (s & 1) * 8192;
        // ---- P1: all reads + half MFMAs; fence reads before barrier
        rdA(Ac); rdB(Bc);
        __builtin_amdgcn_s_setprio(1); mm2(0); __builtin_amdgcn_s_setprio(0);
        asm volatile("s_waitcnt lgkmcnt(0)" ::: "memory");
        PBAR;
        // ---- P2: stage s+2 (buffer s&1 fully read); other half MFMAs
        if (s + 2 < NT) stage(s + 2);
        __builtin_amdgcn_s_setprio(1); mm2(2); __builtin_amdgcn_s_setprio(0);
        if (s + 2 < NT)      asm volatile("s_waitcnt vmcnt(3)" ::: "memory");
        else if (s + 1 < NT) asm volatile("s_waitcnt vmcnt(0)" ::: "memory");
        PBAR;
    }
#undef PBAR

#pragma unroll
    for (int mi = 0; mi < 4; mi++)
#pragma unroll
        for (int nj = 0; nj < 4; nj++)
#pragma unroll
            for (int r = 0; r < 4; r++) {
                size_t row = row0 + wm * 64 + mi * 16 + kg * 4 + r;
                size_t col = col0 + wn * 64 + nj * 16 + lr;
                float vv = acc[mi][nj][r];
                if (EPI == 5) {
                    ((bf16*)outp)[(size_t)split * M * N + row * N + col] = (bf16)vv;
                } else {  // EPI == 4: fused gate/up + silu
                    float pv = __shfl_xor(vv, 1);
                    float g = (lane & 1) ? pv : vv;
                    float u = (lane & 1) ? vv : pv;
                    float sg = g / (1.0f + __expf(-g));
                    if (!(lane & 1))
                        ((bf16*)outp)[row * (size_t)(N >> 1) + (col >> 1)] =
                            (bf16)(sg * u);
                }
            }
}

// ---- reduce: out = resid + sum_s parts[s] (bf16 partials), 8 elems/thr ---
__global__ __launch_bounds__(256) void k_reduce(const bf16* __restrict__ parts,
        const float* __restrict__ resid, float* __restrict__ out,
        int ns, size_t n8) {
    size_t i = (size_t)blockIdx.x * 256 + threadIdx.x;
    if (i >= n8) return;
    size_t base = i * 8;
    float4 a = *(const float4*)(resid + base);
    float4 b = *(const float4*)(resid + base + 4);
    for (int s = 0; s < ns; s++) {
        bf16x8 p = *(const bf16x8*)(parts + (size_t)s * n8 * 8 + base);
        a.x += (float)p[0]; a.y += (float)p[1]; a.z += (float)p[2]; a.w += (float)p[3];
        b.x += (float)p[4]; b.y += (float)p[5]; b.z += (float)p[6]; b.w += (float)p[7];
    }
    *(float4*)(out + base) = a;
    *(float4*)(out + base + 4) = b;
}

// ---- fused: x2 = resid + sum parts(bf16); hb = rmsnorm(x2)*w -------------
__global__ __launch_bounds__(256) void k_reduce_rms(const bf16* __restrict__ parts,
        const float* __restrict__ resid, const float* __restrict__ w,
        float* __restrict__ x2, bf16* __restrict__ hb, int ns) {
    const int H = 2048;
    size_t row = blockIdx.x;
    int base = threadIdx.x * 8;
    const float* rr = resid + row * H + base;
    float4 a = *(const float4*)rr;
    float4 b = *(const float4*)(rr + 4);
    for (int s = 0; s < ns; s++) {
        bf16x8 p = *(const bf16x8*)(parts + (size_t)s * H * 2048 + row * H + base);
        a.x += (float)p[0]; a.y += (float)p[1]; a.z += (float)p[2]; a.w += (float)p[3];
        b.x += (float)p[4]; b.y += (float)p[5]; b.z += (float)p[6]; b.w += (float)p[7];
    }
    *(float4*)(x2 + row * H + base) = a;
    *(float4*)(x2 + row * H + base + 4) = b;
    float ss = a.x*a.x + a.y*a.y + a.z*a.z + a.w*a.w
             + b.x*b.x + b.y*b.y + b.z*b.z + b.w*b.w;
#pragma unroll
    for (int m = 32; m > 0; m >>= 1) ss += __shfl_xor(ss, m);
    __shared__ float red[4];
    if ((threadIdx.x & 63) == 0) red[threadIdx.x >> 6] = ss;
    __syncthreads();
    float tot = red[0] + red[1] + red[2] + red[3];
    float rs = rsqrtf(tot * (1.0f / H) + 1e-5f);
    float4 wa = *(const float4*)(w + base);
    float4 wb = *(const float4*)(w + base + 4);
    bf16x8 ov;
    ov[0] = (bf16)(a.x * rs * wa.x); ov[1] = (bf16)(a.y * rs * wa.y);
    ov[2] = (bf16)(a.z * rs * wa.z); ov[3] = (bf16)(a.w * rs * wa.w);
    ov[4] = (bf16)(b.x * rs * wb.x); ov[5] = (bf16)(b.y * rs * wb.y);
    ov[6] = (bf16)(b.z * rs * wb.z); ov[7] = (bf16)(b.w * rs * wb.w);
    *(bf16x8*)(hb + row * H + base) = ov;
}

// ---- fused QKV finisher: split-K reduce + RoPE + qk-norm + scatter -------
__global__ __launch_bounds__(256) void k_qkvrope(const bf16* __restrict__ parts,
        bf16* __restrict__ qb, bf16* __restrict__ kb, bf16* __restrict__ vb) {
    int s = blockIdx.x;
    int tid = threadIdx.x, wave = tid >> 6, lane = tid & 63;
    const bf16* p0 = parts + (size_t)s * 3072;
    const bf16* p1 = p0 + (size_t)2048 * 3072;
    float f = exp2f((float)lane * -0.2076205059304601f);  // 10000^(-lane/64)
    float sn, cs;
    sincosf((float)s * f, &sn, &cs);
#pragma unroll 1
    for (int pass = 0; pass < 5; pass++) {
        int h = pass * 4 + wave;
        int base = (h < 16) ? h * 128 : 2048 + (h - 16) * 128;
        int c1 = base + lane, c2 = c1 + 64;
        float x1 = (float)p0[c1] + (float)p1[c1];
        float x2 = (float)p0[c2] + (float)p1[c2];
        float o1 = x1 * cs - x2 * sn;
        float o2 = x2 * cs + x1 * sn;
        float ss = o1 * o1 + o2 * o2;
#pragma unroll
        for (int m = 32; m > 0; m >>= 1) ss += __shfl_xor(ss, m);
        float rs = rsqrtf(ss * (1.0f / 128.0f) + 1e-5f);
        bf16* dst = (h < 16) ? (qb + (size_t)s * 2048 + h * 128)
                             : (kb + (size_t)s * 512 + (h - 16) * 128);
        dst[lane] = (bf16)(o1 * rs);
        dst[lane + 64] = (bf16)(o2 * rs);
    }
    int c = 2560 + tid * 2;
    float v0 = (float)p0[c] + (float)p1[c];
    float v1 = (float)p0[c + 1] + (float)p1[c + 1];
    bf16* vd = vb + (size_t)s * 512 + tid * 2;
    vd[0] = (bf16)v0; vd[1] = (bf16)v1;
}

// ------------- flash attention, GQA 16q/4kv, causal, tanh softcap ---------
__global__ __launch_bounds__(256, 2) void k_attn(const bf16* __restrict__ qg,
        const bf16* __restrict__ kgl, const bf16* __restrict__ vtg,
        bf16* __restrict__ og) {
    extern __shared__ char alds[];
    int pi = blockIdx.x, h = blockIdx.y, kvh = h >> 2;
    int qt = (pi & 1) ? (31 - (pi >> 1)) : (pi >> 1);
    int nt = qt + 1;
    int tid = threadIdx.x, wave = tid >> 6, lane = tid & 63;
    int lr = lane & 15, kgrp = lane >> 4;

    int rowQ[4], colQ[4], rowV[4], colV[4];
#pragma unroll
    for (int j = 0; j < 4; j++) {
        int p = j * 4096 + wave * 1024 + lane * 16;
        int ps = p ^ (((p >> 8) & 7) << 4);
        rowQ[j] = ps >> 8; colQ[j] = ps & 255;
        int pv = p ^ (((p >> 7) & 7) << 4);
        rowV[j] = pv >> 7; colV[j] = pv & 127;
    }

    const float C1 = 0.08838834764831845f / 50.0f;  // 1/(50*sqrt(128))
    const float L2E50 = 72.13475204444817f;         // 50*log2(e)

#pragma unroll
    for (int j = 0; j < 4; j++)
        GLP16((const char*)qg + (size_t)(qt * 64 + rowQ[j]) * 4096 + h * 256 + colQ[j],
              alds + j * 4096 + wave * 1024);
    for (int t = 0; t < 2 && t < nt; t++) {
#pragma unroll
        for (int j = 0; j < 4; j++)
            GLP16((const char*)kgl + (size_t)(t * 64 + rowQ[j]) * 1024 + kvh * 256 + colQ[j],
                  alds + 16384 + t * 16384 + j * 4096 + wave * 1024);
#pragma unroll
        for (int j = 0; j < 4; j++)
            GLP16((const char*)vtg + (size_t)(kvh * 128 + rowV[j]) * 4096 + t * 128 + colV[j],
                  alds + 49152 + t * 16384 + j * 4096 + wave * 1024);
    }
    if (nt > 1) asm volatile("s_waitcnt vmcnt(8)" ::: "memory");
    else        asm volatile("s_waitcnt vmcnt(0)" ::: "memory");
    __builtin_amdgcn_s_barrier();

    bf16x8 qf[4];
#pragma unroll
    for (int c = 0; c < 4; c++) {
        int b = (wave * 16 + lr) * 256 + c * 64 + kgrp * 16;
        qf[c] = *(const bf16x8*)(alds + (b ^ (((b >> 8) & 7) << 4)));
    }
    __builtin_amdgcn_s_barrier();

    f32x4 accO[8];
#pragma unroll
    for (int n = 0; n < 8; n++) accO[n] = (f32x4){0, 0, 0, 0};
    float lsum[4] = {0, 0, 0, 0};
    int qrow = qt * 64 + wave * 16 + kgrp * 4;

    for (int kt = 0; kt < nt; kt++) {
        int buf = kt & 1;
        const char* Kb = alds + 16384 + buf * 16384;
        const char* Vb = alds + 49152 + buf * 16384;
        char* Pb = alds;
#pragma unroll
        for (int j = 0; j < 4; j++) {
            f32x4 s = {0, 0, 0, 0};
#pragma unroll
            for (int c = 0; c < 4; c++) {
                int b = (j * 16 + lr) * 256 + c * 64 + kgrp * 16;
                bf16x8 kf = *(const bf16x8*)(Kb + (b ^ (((b >> 8) & 7) << 4)));
                s = mfma16(qf[c], kf, s);
            }
            int key = kt * 64 + j * 16 + lr;
#pragma unroll
            for (int r = 0; r < 4; r++) {
                float y = s[r] * C1;
                float y2 = y * y;
                float u = fmaf(y2, 0.13333333f, -0.33333333f);
                u = fmaf(y2, u, 1.0f);
                float t5 = y * u;                       // tanh(y)
                float pe = fmaf(t5, L2E50, -L2E50);     // (50t-50)*log2e
                float pv = (key <= qrow + r) ? exp2f(pe) : 0.0f;
                lsum[r] += pv;
                int wb = (wave * 16 + kgrp * 4 + r) * 128 + (j * 16 + lr) * 2;
                *(bf16*)(Pb + (wb ^ (((wb >> 7) & 7) << 4))) = (bf16)pv;
            }
        }
        bf16x8 pf[2];
#pragma unroll
        for (int ks2 = 0; ks2 < 2; ks2++) {
            int b = (wave * 16 + lr) * 128 + ks2 * 64 + kgrp * 16;
            pf[ks2] = *(const bf16x8*)(Pb + (b ^ (((b >> 7) & 7) << 4)));
        }
#pragma unroll
        for (int n = 0; n < 8; n++)
#pragma unroll
            for (int ks2 = 0; ks2 < 2; ks2++) {
                int b = (n * 16 + lr) * 128 + ks2 * 64 + kgrp * 16;
                bf16x8 vf = *(const bf16x8*)(Vb + (b ^ (((b >> 7) & 7) << 4)));
                accO[n] = mfma16(pf[ks2], vf, accO[n]);
            }
        __builtin_amdgcn_s_barrier();
        bool more = (kt + 2 < nt);
        if (more) {
            int t = kt + 2;
#pragma unroll
            for (int j = 0; j < 4; j++)
                GLP16((const char*)kgl + (size_t)(t * 64 + rowQ[j]) * 1024 + kvh * 256 + colQ[j],
                      alds + 16384 + buf * 16384 + j * 4096 + wave * 1024);
#pragma unroll
            for (int j = 0; j < 4; j++)
                GLP16((const char*)vtg + (size_t)(kvh * 128 + rowV[j]) * 4096 + t * 128 + colV[j],
                      alds + 49152 + buf * 16384 + j * 4096 + wave * 1024);
        }
        if (kt + 1 < nt) {
            if (more) asm volatile("s_waitcnt vmcnt(8)" ::: "memory");
            else      asm volatile("s_waitcnt vmcnt(0)" ::: "memory");
            __builtin_amdgcn_s_barrier();
        }
    }
#pragma unroll
    for (int r = 0; r < 4; r++) {
        float t = lsum[r];
        t += __shfl_xor(t, 1); t += __shfl_xor(t, 2);
        t += __shfl_xor(t, 4); t += __shfl_xor(t, 8);
        lsum[r] = t;
    }
#pragma unroll
    for (int n = 0; n < 8; n++)
#pragma unroll
        for (int r = 0; r < 4; r++) {
            size_t row = qt * 64 + wave * 16 + kgrp * 4 + r;
            og[row * 2048 + h * 128 + n * 16 + lr] = (bf16)(accO[n][r] / lsum[r]);
        }
}

// --------------------------------------------------------------------------
extern "C" void kernel_launch(void* const* d_in, const int* in_sizes, int n_in,
                              void* d_out, int out_size, void* d_ws, size_t ws_size,
                              hipStream_t stream) {
    const float* x      = (const float*)d_in[0];
    const float* attn_w = (const float*)d_in[1];
    const float* mlp_w  = (const float*)d_in[2];
    const float* wq     = (const float*)d_in[3];
    const float* wk     = (const float*)d_in[4];
    const float* wv     = (const float*)d_in[5];
    const float* wo     = (const float*)d_in[6];
    const float* wgate  = (const float*)d_in[7];
    const float* wup    = (const float*)d_in[8];
    const float* wdown  = (const float*)d_in[9];
    float* out = (float*)d_out;
    char* ws = (char*)d_ws;

    const size_t MB = 1024 * 1024;
    // timeline-disjoint workspace map:
    bf16* Wqkv = (bf16*)(ws + 0);        // [0,12.6) step 2-3
    bf16* vt   = (bf16*)(ws + 0);        // [0,2)    step 4-6 (Wqkv dead)
    bf16* pO   = (bf16*)(ws + 0);        // [0,33.5) O partials split4 (vt dead)
    bf16* Wgu  = (bf16*)(ws + 0);        // [0,64)   interleaved gate/up (pO dead)
    bf16* pD   = (bf16*)(ws + 0);        // [0,33.5) down partials (Wgu dead)
    bf16* WoT  = (bf16*)(ws + 64 * MB);  // [64,72)  step 7
    bf16* WdT  = (bf16*)(ws + 64 * MB);  // [64,96)  step 10 (WoT dead)
    bf16* hb   = (bf16*)(ws + 96 * MB);  // 8MB
    bf16* qb   = (bf16*)(ws + 104 * MB); // 8MB
    bf16* kb   = (bf16*)(ws + 112 * MB); // 2MB
    bf16* vb   = (bf16*)(ws + 114 * MB); // 2MB
    bf16* ob   = (bf16*)(ws + 116 * MB); // 8MB
    float* x2  = (float*)(ws + 124 * MB);// 16MB
    bf16* gb   = (bf16*)(ws + 140 * MB); // 32MB silu(g)*u
    bf16* pQ   = (bf16*)(ws + 172 * MB); // [172,198) QKV partials (bf16)

    const int LDS9 = 49152;
    hipFuncSetAttribute((const void*)&k_gemm9<4>,
        hipFuncAttributeMaxDynamicSharedMemorySize, LDS9);
    hipFuncSetAttribute((const void*)&k_gemm9<5>,
        hipFuncAttributeMaxDynamicSharedMemorySize, LDS9);
    const int LDSA = 81920;
    hipFuncSetAttribute((const void*)&k_attn,
        hipFuncAttributeMaxDynamicSharedMemorySize, LDSA);

    const size_t n8 = (size_t)2048 * 2048 / 8;

    // 1. attn RMSNorm
    k_rmsnorm<<<2048, 256, 0, stream>>>(x, attn_w, hb);
    // 2. convert QKV weights into one [3072][2048] bf16 Bt
    k_convT<<<dim3(32, 32), 256, 0, stream>>>(wq, Wqkv, 2048, 2048, 1, 0);
    k_convT<<<dim3(32, 8), 256, 0, stream>>>(wk, Wqkv + 4194304, 2048, 512, 1, 0);
    k_convT<<<dim3(32, 8), 256, 0, stream>>>(wv, Wqkv + 5242880, 2048, 512, 1, 0);
    // 3. fused QKV projection, split-K=2 -> bf16 partials
    k_gemm9<5><<<dim3(24, 8, 2), 512, LDS9, stream>>>(hb, Wqkv, pQ, nullptr,
                                                      2048, 3072, 2048, 1024);
    // 4. fused reduce + RoPE + qk-norm + scatter
    k_qkvrope<<<2048, 256, 0, stream>>>(pQ, qb, kb, vb);
    // 5. V transpose (vb[2048][512] -> vt[512][2048]); Wqkv dead now
    k_transpose<<<dim3(64, 16), 256, 0, stream>>>(vb, vt, 2048, 512);
    // 6. attention (complementary pairing, 2 blocks/CU)
    k_attn<<<dim3(32, 16), 256, LDSA, stream>>>(qb, kb, vt, ob);
    // 7. O projection, split-K=4 -> bf16 partials; fused reduce+rmsnorm
    k_convT<<<dim3(32, 32), 256, 0, stream>>>(wo, WoT, 2048, 2048, 1, 0);
    k_gemm9<5><<<dim3(16, 8, 4), 512, LDS9, stream>>>(ob, WoT, pO, nullptr,
                                                      2048, 2048, 2048, 512);
    k_reduce_rms<<<2048, 256, 0, stream>>>(pO, x, mlp_w, x2, hb, 4);
    // 8. convert gate (even rows) + up (odd rows) interleaved [16384][2048]
    k_convT<<<dim3(32, 128), 256, 0, stream>>>(wgate, Wgu, 2048, 8192, 2, 0);
    k_convT<<<dim3(32, 128), 256, 0, stream>>>(wup, Wgu, 2048, 8192, 2, 1);
    // 9. fused gate+up GEMM with in-register silu epilogue -> gb
    k_gemm9<4><<<dim3(128, 8, 1), 512, LDS9, stream>>>(hb, Wgu, gb, nullptr,
                                                       2048, 16384, 2048, 2048);
    // 10. down GEMM, split-K=4 -> bf16 partials; reduce + residual -> out
    k_convT<<<dim3(128, 32), 256, 0, stream>>>(wdown, WdT, 8192, 2048, 1, 0);
    k_gemm9<5><<<dim3(16, 8, 4), 512, LDS9, stream>>>(gb, WdT, pD, nullptr,
                                                      2048, 2048, 8192, 2048);
    k_reduce<<<2048, 256, 0, stream>>>(pD, x2, out, 4, n8);
}

// Round 13
// 463.137 us; speedup vs baseline: 1.0220x; 1.0220x over previous
//
#include <hip/hip_runtime.h>

typedef __bf16 bf16;
typedef __bf16 bf16x4 __attribute__((ext_vector_type(4)));
typedef __bf16 bf16x8 __attribute__((ext_vector_type(8)));
typedef float f32x4 __attribute__((ext_vector_type(4)));
typedef float f32x16 __attribute__((ext_vector_type(16)));

#define GLP16(gp, lp) __builtin_amdgcn_global_load_lds( \
    (const __attribute__((address_space(1))) void*)(gp), \
    (__attribute__((address_space(3))) void*)(lp), 16, 0, 0)

__device__ __forceinline__ f32x4 mfma16(bf16x8 a, bf16x8 b, f32x4 c) {
    return __builtin_amdgcn_mfma_f32_16x16x32_bf16(a, b, c, 0, 0, 0);
}
__device__ __forceinline__ f32x16 mfma32(bf16x8 a, bf16x8 b, f32x16 c) {
    return __builtin_amdgcn_mfma_f32_32x32x16_bf16(a, b, c, 0, 0, 0);
}

// ---------------- RMSNorm: fp32 in -> bf16 out, row = 2048 ----------------
__global__ __launch_bounds__(256) void k_rmsnorm(const float* __restrict__ x,
        const float* __restrict__ w, bf16* __restrict__ out) {
    const int H = 2048;
    size_t row = blockIdx.x;
    const float* xr = x + row * H;
    int base = threadIdx.x * 8;
    float4 a = *(const float4*)(xr + base);
    float4 b = *(const float4*)(xr + base + 4);
    float ss = a.x*a.x + a.y*a.y + a.z*a.z + a.w*a.w
             + b.x*b.x + b.y*b.y + b.z*b.z + b.w*b.w;
#pragma unroll
    for (int m = 32; m > 0; m >>= 1) ss += __shfl_xor(ss, m);
    __shared__ float red[4];
    if ((threadIdx.x & 63) == 0) red[threadIdx.x >> 6] = ss;
    __syncthreads();
    float tot = red[0] + red[1] + red[2] + red[3];
    float rs = rsqrtf(tot * (1.0f / H) + 1e-5f);
    float4 wa = *(const float4*)(w + base);
    float4 wb = *(const float4*)(w + base + 4);
    bf16x8 ov;
    ov[0] = (bf16)(a.x * rs * wa.x); ov[1] = (bf16)(a.y * rs * wa.y);
    ov[2] = (bf16)(a.z * rs * wa.z); ov[3] = (bf16)(a.w * rs * wa.w);
    ov[4] = (bf16)(b.x * rs * wb.x); ov[5] = (bf16)(b.y * rs * wb.y);
    ov[6] = (bf16)(b.z * rs * wb.z); ov[7] = (bf16)(b.w * rs * wb.w);
    *(bf16x8*)(out + row * H + base) = ov;
}

// ------- convT v2: W (K x N fp32) -> Wt (N*rmul+roff rows, K bf16 cols) ---
__global__ __launch_bounds__(256) void k_convT(const float* __restrict__ W,
        bf16* __restrict__ Wt, int K, int N, int rmul, int roff) {
    __shared__ float t[64][65];
    int k0 = blockIdx.x * 64, n0 = blockIdx.y * 64;
    int tid = threadIdx.x;
#pragma unroll
    for (int it = 0; it < 4; it++) {
        int idx = it * 256 + tid;
        int r = idx >> 4, c = (idx & 15) * 4;
        float4 v = *(const float4*)(W + (size_t)(k0 + r) * N + n0 + c);
        t[r][c] = v.x; t[r][c + 1] = v.y; t[r][c + 2] = v.z; t[r][c + 3] = v.w;
    }
    __syncthreads();
#pragma unroll
    for (int it = 0; it < 4; it++) {
        int idx = it * 256 + tid;
        int n = idx >> 4, kc = (idx & 15) * 4;
        bf16x4 o;
#pragma unroll
        for (int j = 0; j < 4; j++) o[j] = (bf16)t[kc + j][n];
        *(bf16x4*)(Wt + ((size_t)(n0 + n) * rmul + roff) * K + k0 + kc) = o;
    }
}

// ------- bf16 transpose: in (R x C) -> out (C x R) ------------------------
__global__ __launch_bounds__(256) void k_transpose(const bf16* __restrict__ in,
        bf16* __restrict__ out, int R, int C) {
    __shared__ bf16 t[32][33];
    int r0 = blockIdx.x * 32, c0 = blockIdx.y * 32;
    int tx = threadIdx.x & 31, ty = threadIdx.x >> 5;
#pragma unroll
    for (int i = 0; i < 4; i++)
        t[ty + i * 8][tx] = in[(size_t)(r0 + ty + i * 8) * C + c0 + tx];
    __syncthreads();
#pragma unroll
    for (int i = 0; i < 4; i++)
        out[(size_t)(c0 + ty + i * 8) * R + r0 + tx] = t[tx][ty + i * 8];
}

// ---------------- GEMM v10: gemm8 schedule + 32x32x16 MFMA ----------------
// BM=BN=256, BK=64, 8 waves (2M x 4N), per-wave 128x64 (4x2 blocks of 32).
// LDS 128KB: A dbuf 2x32KB @0, B dbuf 2x32KB @64KB; one row per 128B line,
// XOR-swizzled byte^=((row&7)<<4) (uniform 8 lanes/slot = b128 floor).
// Operand layout (gfx950 verified): A row=lane&31, k=(lane>>5)*8+e;
// C/D col=lane&31, row=(reg&3)+8*(reg>>2)+4*(lane>>5).
// Per K-tile: P1 {rd A-blk0/1 + all B (16 rds) | stage t+1 (8 GLP) |
// 16 MFMA | barrier}; P2 {rd A-blk2/3 (8 rds, reuse regs) | 16 MFMA |
// vmcnt(0) free-drain | barrier}.
// EPI: 4 = fused gate/up silu (even cols = gate), 5 = bf16 partial (split-K)
template<int EPI>
__global__ __launch_bounds__(512, 2) void k_gemm10(const bf16* __restrict__ A,
        const bf16* __restrict__ Bt, void* __restrict__ outp,
        const void* __restrict__ aux, int M, int N, int K, int ksplit) {
    extern __shared__ char lds[];
    const int tid = threadIdx.x, wave = tid >> 6, lane = tid & 63;
    const int l31 = lane & 31, lh = lane >> 5;
    const int wm = wave >> 2, wn = wave & 3;
    const int bn = blockIdx.x, bm = blockIdx.y, split = blockIdx.z;
    const int row0 = bm * 256, col0 = bn * 256;
    const int kbeg = split * ksplit;
    const int NT = ksplit >> 6;
    const size_t K2 = (size_t)K * 2;

    // staging: linear dest byte d in 32KB tile -> pre-swizzled source offset
    int soff[4];
#pragma unroll
    for (int c = 0; c < 4; c++) {
        int d = c * 8192 + tid * 16;
        int rh = d >> 7, w = d & 127;
        soff[c] = rh * (int)K2 + (w ^ ((rh & 7) << 4));
    }
    const char* Ab = (const char*)A + ((size_t)row0 * K + kbeg) * 2;
    const char* Bb = (const char*)Bt + ((size_t)col0 * K + kbeg) * 2;

    auto stage = [&](int t) {
        const char* sa = Ab + (size_t)t * 128;
        char* da = lds + (t & 1) * 32768 + wave * 1024;
        const char* sb = Bb + (size_t)t * 128;
        char* db = lds + 65536 + (t & 1) * 32768 + wave * 1024;
#pragma unroll
        for (int c = 0; c < 4; c++) {
            GLP16(sa + soff[c], da + c * 8192);
            GLP16(sb + soff[c], db + c * 8192);
        }
    };

    f32x16 acc[4][2];
#pragma unroll
    for (int m = 0; m < 4; m++)
#pragma unroll
        for (int n = 0; n < 2; n++) acc[m][n] = (f32x16)(0.0f);

    bf16x8 a0[4], a1[4], b0[4], b1[4];
    auto rdA = [&](const char* base, int mb, bf16x8 (&arr)[4]) {
        int line = wm * 128 + mb * 32 + l31;
        const char* p = base + line * 128;
        int xr = (line & 7) << 4;
#pragma unroll
        for (int ks = 0; ks < 4; ks++)
            arr[ks] = *(const bf16x8*)(p + ((ks * 32 + lh * 16) ^ xr));
    };
    auto rdB = [&](const char* base, int nb, bf16x8 (&arr)[4]) {
        int line = wn * 64 + nb * 32 + l31;
        const char* p = base + line * 128;
        int xr = (line & 7) << 4;
#pragma unroll
        for (int ks = 0; ks < 4; ks++)
            arr[ks] = *(const bf16x8*)(p + ((ks * 32 + lh * 16) ^ xr));
    };
    auto mm = [&](int mb, bf16x8 (&af)[4]) {
#pragma unroll
        for (int ks = 0; ks < 4; ks++) acc[mb][0] = mfma32(af[ks], b0[ks], acc[mb][0]);
#pragma unroll
        for (int ks = 0; ks < 4; ks++) acc[mb][1] = mfma32(af[ks], b1[ks], acc[mb][1]);
    };

#define PBAR do { asm volatile("" ::: "memory"); \
                  __builtin_amdgcn_s_barrier(); \
                  asm volatile("" ::: "memory"); } while (0)

    stage(0);
    asm volatile("s_waitcnt vmcnt(0)" ::: "memory");
    PBAR;

    for (int t = 0; t < NT; ++t) {
        const char* Ac = lds + (t & 1) * 32768;
        const char* Bc = lds + 65536 + (t & 1) * 32768;
        const bool m1 = (t + 1 < NT);
        // ---- P1: A-blocks 0,1 + all B; stage next tile; 16 MFMA
        rdA(Ac, 0, a0); rdA(Ac, 1, a1); rdB(Bc, 0, b0); rdB(Bc, 1, b1);
        if (m1) stage(t + 1);
        __builtin_amdgcn_s_setprio(1);
        mm(0, a0); mm(1, a1);
        __builtin_amdgcn_s_setprio(0);
        PBAR;
        // ---- P2: A-blocks 2,3 (reuse regs); 16 MFMA; free drain
        rdA(Ac, 2, a0); rdA(Ac, 3, a1);
        __builtin_amdgcn_s_setprio(1);
        mm(2, a0); mm(3, a1);
        __builtin_amdgcn_s_setprio(0);
        if (m1) asm volatile("s_waitcnt vmcnt(0)" ::: "memory");
        PBAR;
    }
#undef PBAR

#pragma unroll
    for (int mb = 0; mb < 4; mb++)
#pragma unroll
        for (int nb = 0; nb < 2; nb++)
#pragma unroll
            for (int g = 0; g < 4; g++)
#pragma unroll
                for (int r = 0; r < 4; r++) {
                    size_t row = row0 + wm * 128 + mb * 32 + r + 8 * g + 4 * lh;
                    size_t col = col0 + wn * 64 + nb * 32 + l31;
                    float vv = acc[mb][nb][g * 4 + r];
                    if (EPI == 5) {
                        ((bf16*)outp)[(size_t)split * M * N + row * N + col] = (bf16)vv;
                    } else {  // EPI == 4: fused gate/up + silu
                        float pv = __shfl_xor(vv, 1);
                        float g2 = (lane & 1) ? pv : vv;
                        float u = (lane & 1) ? vv : pv;
                        float sg = g2 / (1.0f + __expf(-g2));
                        if (!(lane & 1))
                            ((bf16*)outp)[row * (size_t)(N >> 1) + (col >> 1)] =
                                (bf16)(sg * u);
                    }
                }
}

// ---- reduce: out = resid + sum_s parts[s] (bf16 partials), 8 elems/thr ---
__global__ __launch_bounds__(256) void k_reduce(const bf16* __restrict__ parts,
        const float* __restrict__ resid, float* __restrict__ out,
        int ns, size_t n8) {
    size_t i = (size_t)blockIdx.x * 256 + threadIdx.x;
    if (i >= n8) return;
    size_t base = i * 8;
    float4 a = *(const float4*)(resid + base);
    float4 b = *(const float4*)(resid + base + 4);
    for (int s = 0; s < ns; s++) {
        bf16x8 p = *(const bf16x8*)(parts + (size_t)s * n8 * 8 + base);
        a.x += (float)p[0]; a.y += (float)p[1]; a.z += (float)p[2]; a.w += (float)p[3];
        b.x += (float)p[4]; b.y += (float)p[5]; b.z += (float)p[6]; b.w += (float)p[7];
    }
    *(float4*)(out + base) = a;
    *(float4*)(out + base + 4) = b;
}

// ---- fused: x2 = resid + sum parts(bf16); hb = rmsnorm(x2)*w -------------
__global__ __launch_bounds__(256) void k_reduce_rms(const bf16* __restrict__ parts,
        const float* __restrict__ resid, const float* __restrict__ w,
        float* __restrict__ x2, bf16* __restrict__ hb, int ns) {
    const int H = 2048;
    size_t row = blockIdx.x;
    int base = threadIdx.x * 8;
    const float* rr = resid + row * H + base;
    float4 a = *(const float4*)rr;
    float4 b = *(const float4*)(rr + 4);
    for (int s = 0; s < ns; s++) {
        bf16x8 p = *(const bf16x8*)(parts + (size_t)s * H * 2048 + row * H + base);
        a.x += (float)p[0]; a.y += (float)p[1]; a.z += (float)p[2]; a.w += (float)p[3];
        b.x += (float)p[4]; b.y += (float)p[5]; b.z += (float)p[6]; b.w += (float)p[7];
    }
    *(float4*)(x2 + row * H + base) = a;
    *(float4*)(x2 + row * H + base + 4) = b;
    float ss = a.x*a.x + a.y*a.y + a.z*a.z + a.w*a.w
             + b.x*b.x + b.y*b.y + b.z*b.z + b.w*b.w;
#pragma unroll
    for (int m = 32; m > 0; m >>= 1) ss += __shfl_xor(ss, m);
    __shared__ float red[4];
    if ((threadIdx.x & 63) == 0) red[threadIdx.x >> 6] = ss;
    __syncthreads();
    float tot = red[0] + red[1] + red[2] + red[3];
    float rs = rsqrtf(tot * (1.0f / H) + 1e-5f);
    float4 wa = *(const float4*)(w + base);
    float4 wb = *(const float4*)(w + base + 4);
    bf16x8 ov;
    ov[0] = (bf16)(a.x * rs * wa.x); ov[1] = (bf16)(a.y * rs * wa.y);
    ov[2] = (bf16)(a.z * rs * wa.z); ov[3] = (bf16)(a.w * rs * wa.w);
    ov[4] = (bf16)(b.x * rs * wb.x); ov[5] = (bf16)(b.y * rs * wb.y);
    ov[6] = (bf16)(b.z * rs * wb.z); ov[7] = (bf16)(b.w * rs * wb.w);
    *(bf16x8*)(hb + row * H + base) = ov;
}

// ---- fused QKV finisher: split-K reduce + RoPE + qk-norm + scatter -------
__global__ __launch_bounds__(256) void k_qkvrope(const bf16* __restrict__ parts,
        bf16* __restrict__ qb, bf16* __restrict__ kb, bf16* __restrict__ vb) {
    int s = blockIdx.x;
    int tid = threadIdx.x, wave = tid >> 6, lane = tid & 63;
    const bf16* p0 = parts + (size_t)s * 3072;
    const bf16* p1 = p0 + (size_t)2048 * 3072;
    float f = exp2f((float)lane * -0.2076205059304601f);  // 10000^(-lane/64)
    float sn, cs;
    sincosf((float)s * f, &sn, &cs);
#pragma unroll 1
    for (int pass = 0; pass < 5; pass++) {
        int h = pass * 4 + wave;
        int base = (h < 16) ? h * 128 : 2048 + (h - 16) * 128;
        int c1 = base + lane, c2 = c1 + 64;
        float x1 = (float)p0[c1] + (float)p1[c1];
        float x2 = (float)p0[c2] + (float)p1[c2];
        float o1 = x1 * cs - x2 * sn;
        float o2 = x2 * cs + x1 * sn;
        float ss = o1 * o1 + o2 * o2;
#pragma unroll
        for (int m = 32; m > 0; m >>= 1) ss += __shfl_xor(ss, m);
        float rs = rsqrtf(ss * (1.0f / 128.0f) + 1e-5f);
        bf16* dst = (h < 16) ? (qb + (size_t)s * 2048 + h * 128)
                             : (kb + (size_t)s * 512 + (h - 16) * 128);
        dst[lane] = (bf16)(o1 * rs);
        dst[lane + 64] = (bf16)(o2 * rs);
    }
    int c = 2560 + tid * 2;
    float v0 = (float)p0[c] + (float)p1[c];
    float v1 = (float)p0[c + 1] + (float)p1[c + 1];
    bf16* vd = vb + (size_t)s * 512 + tid * 2;
    vd[0] = (bf16)v0; vd[1] = (bf16)v1;
}

// ------------- flash attention, GQA 16q/4kv, causal, tanh softcap ---------
__global__ __launch_bounds__(256, 2) void k_attn(const bf16* __restrict__ qg,
        const bf16* __restrict__ kgl, const bf16* __restrict__ vtg,
        bf16* __restrict__ og) {
    extern __shared__ char alds[];
    int pi = blockIdx.x, h = blockIdx.y, kvh = h >> 2;
    int qt = (pi & 1) ? (31 - (pi >> 1)) : (pi >> 1);
    int nt = qt + 1;
    int tid = threadIdx.x, wave = tid >> 6, lane = tid & 63;
    int lr = lane & 15, kgrp = lane >> 4;

    int rowQ[4], colQ[4], rowV[4], colV[4];
#pragma unroll
    for (int j = 0; j < 4; j++) {
        int p = j * 4096 + wave * 1024 + lane * 16;
        int ps = p ^ (((p >> 8) & 7) << 4);
        rowQ[j] = ps >> 8; colQ[j] = ps & 255;
        int pv = p ^ (((p >> 7) & 7) << 4);
        rowV[j] = pv >> 7; colV[j] = pv & 127;
    }

    const float C1 = 0.08838834764831845f / 50.0f;  // 1/(50*sqrt(128))
    const float L2E50 = 72.13475204444817f;         // 50*log2(e)

#pragma unroll
    for (int j = 0; j < 4; j++)
        GLP16((const char*)qg + (size_t)(qt * 64 + rowQ[j]) * 4096 + h * 256 + colQ[j],
              alds + j * 4096 + wave * 1024);
    for (int t = 0; t < 2 && t < nt; t++) {
#pragma unroll
        for (int j = 0; j < 4; j++)
            GLP16((const char*)kgl + (size_t)(t * 64 + rowQ[j]) * 1024 + kvh * 256 + colQ[j],
                  alds + 16384 + t * 16384 + j * 4096 + wave * 1024);
#pragma unroll
        for (int j = 0; j < 4; j++)
            GLP16((const char*)vtg + (size_t)(kvh * 128 + rowV[j]) * 4096 + t * 128 + colV[j],
                  alds + 49152 + t * 16384 + j * 4096 + wave * 1024);
    }
    if (nt > 1) asm volatile("s_waitcnt vmcnt(8)" ::: "memory");
    else        asm volatile("s_waitcnt vmcnt(0)" ::: "memory");
    __builtin_amdgcn_s_barrier();

    bf16x8 qf[4];
#pragma unroll
    for (int c = 0; c < 4; c++) {
        int b = (wave * 16 + lr) * 256 + c * 64 + kgrp * 16;
        qf[c] = *(const bf16x8*)(alds + (b ^ (((b >> 8) & 7) << 4)));
    }
    __builtin_amdgcn_s_barrier();

    f32x4 accO[8];
#pragma unroll
    for (int n = 0; n < 8; n++) accO[n] = (f32x4){0, 0, 0, 0};
    float lsum[4] = {0, 0, 0, 0};
    int qrow = qt * 64 + wave * 16 + kgrp * 4;

    for (int kt = 0; kt < nt; kt++) {
        int buf = kt & 1;
        const char* Kb = alds + 16384 + buf * 16384;
        const char* Vb = alds + 49152 + buf * 16384;
        char* Pb = alds;
#pragma unroll
        for (int j = 0; j < 4; j++) {
            f32x4 s = {0, 0, 0, 0};
#pragma unroll
            for (int c = 0; c < 4; c++) {
                int b = (j * 16 + lr) * 256 + c * 64 + kgrp * 16;
                bf16x8 kf = *(const bf16x8*)(Kb + (b ^ (((b >> 8) & 7) << 4)));
                s = mfma16(qf[c], kf, s);
            }
            int key = kt * 64 + j * 16 + lr;
#pragma unroll
            for (int r = 0; r < 4; r++) {
                float y = s[r] * C1;
                float y2 = y * y;
                float u = fmaf(y2, 0.13333333f, -0.33333333f);
                u = fmaf(y2, u, 1.0f);
                float t5 = y * u;                       // tanh(y)
                float pe = fmaf(t5, L2E50, -L2E50);     // (50t-50)*log2e
                float pv = (key <= qrow + r) ? exp2f(pe) : 0.0f;
                lsum[r] += pv;
                int wb = (wave * 16 + kgrp * 4 + r) * 128 + (j * 16 + lr) * 2;
                *(bf16*)(Pb + (wb ^ (((wb >> 7) & 7) << 4))) = (bf16)pv;
            }
        }
        bf16x8 pf[2];
#pragma unroll
        for (int ks2 = 0; ks2 < 2; ks2++) {
            int b = (wave * 16 + lr) * 128 + ks2 * 64 + kgrp * 16;
            pf[ks2] = *(const bf16x8*)(Pb + (b ^ (((b >> 7) & 7) << 4)));
        }
#pragma unroll
        for (int n = 0; n < 8; n++)
#pragma unroll
            for (int ks2 = 0; ks2 < 2; ks2++) {
                int b = (n * 16 + lr) * 128 + ks2 * 64 + kgrp * 16;
                bf16x8 vf = *(const bf16x8*)(Vb + (b ^ (((b >> 7) & 7) << 4)));
                accO[n] = mfma16(pf[ks2], vf, accO[n]);
            }
        __builtin_amdgcn_s_barrier();
        bool more = (kt + 2 < nt);
        if (more) {
            int t = kt + 2;
#pragma unroll
            for (int j = 0; j < 4; j++)
                GLP16((const char*)kgl + (size_t)(t * 64 + rowQ[j]) * 1024 + kvh * 256 + colQ[j],
                      alds + 16384 + buf * 16384 + j * 4096 + wave * 1024);
#pragma unroll
            for (int j = 0; j < 4; j++)
                GLP16((const char*)vtg + (size_t)(kvh * 128 + rowV[j]) * 4096 + t * 128 + colV[j],
                      alds + 49152 + buf * 16384 + j * 4096 + wave * 1024);
        }
        if (kt + 1 < nt) {
            if (more) asm volatile("s_waitcnt vmcnt(8)" ::: "memory");
            else      asm volatile("s_waitcnt vmcnt(0)" ::: "memory");
            __builtin_amdgcn_s_barrier();
        }
    }
#pragma unroll
    for (int r = 0; r < 4; r++) {
        float t = lsum[r];
        t += __shfl_xor(t, 1); t += __shfl_xor(t, 2);
        t += __shfl_xor(t, 4); t += __shfl_xor(t, 8);
        lsum[r] = t;
    }
#pragma unroll
    for (int n = 0; n < 8; n++)
#pragma unroll
        for (int r = 0; r < 4; r++) {
            size_t row = qt * 64 + wave * 16 + kgrp * 4 + r;
            og[row * 2048 + h * 128 + n * 16 + lr] = (bf16)(accO[n][r] / lsum[r]);
        }
}

// --------------------------------------------------------------------------
extern "C" void kernel_launch(void* const* d_in, const int* in_sizes, int n_in,
                              void* d_out, int out_size, void* d_ws, size_t ws_size,
                              hipStream_t stream) {
    const float* x      = (const float*)d_in[0];
    const float* attn_w = (const float*)d_in[1];
    const float* mlp_w  = (const float*)d_in[2];
    const float* wq     = (const float*)d_in[3];
    const float* wk     = (const float*)d_in[4];
    const float* wv     = (const float*)d_in[5];
    const float* wo     = (const float*)d_in[6];
    const float* wgate  = (const float*)d_in[7];
    const float* wup    = (const float*)d_in[8];
    const float* wdown  = (const float*)d_in[9];
    float* out = (float*)d_out;
    char* ws = (char*)d_ws;

    const size_t MB = 1024 * 1024;
    // timeline-disjoint workspace map:
    bf16* Wqkv = (bf16*)(ws + 0);        // [0,12.6) step 2-3
    bf16* vt   = (bf16*)(ws + 0);        // [0,2)    step 4-6 (Wqkv dead)
    bf16* pO   = (bf16*)(ws + 0);        // [0,33.5) O partials split4 (vt dead)
    bf16* Wgu  = (bf16*)(ws + 0);        // [0,64)   interleaved gate/up (pO dead)
    bf16* pD   = (bf16*)(ws + 0);        // [0,33.5) down partials (Wgu dead)
    bf16* WoT  = (bf16*)(ws + 64 * MB);  // [64,72)  step 7
    bf16* WdT  = (bf16*)(ws + 64 * MB);  // [64,96)  step 10 (WoT dead)
    bf16* hb   = (bf16*)(ws + 96 * MB);  // 8MB
    bf16* qb   = (bf16*)(ws + 104 * MB); // 8MB
    bf16* kb   = (bf16*)(ws + 112 * MB); // 2MB
    bf16* vb   = (bf16*)(ws + 114 * MB); // 2MB
    bf16* ob   = (bf16*)(ws + 116 * MB); // 8MB
    float* x2  = (float*)(ws + 124 * MB);// 16MB
    bf16* gb   = (bf16*)(ws + 140 * MB); // 32MB silu(g)*u
    bf16* pQ   = (bf16*)(ws + 172 * MB); // [172,198) QKV partials (bf16)

    const int LDS10 = 131072;
    hipFuncSetAttribute((const void*)&k_gemm10<4>,
        hipFuncAttributeMaxDynamicSharedMemorySize, LDS10);
    hipFuncSetAttribute((const void*)&k_gemm10<5>,
        hipFuncAttributeMaxDynamicSharedMemorySize, LDS10);
    const int LDSA = 81920;
    hipFuncSetAttribute((const void*)&k_attn,
        hipFuncAttributeMaxDynamicSharedMemorySize, LDSA);

    const size_t n8 = (size_t)2048 * 2048 / 8;

    // 1. attn RMSNorm
    k_rmsnorm<<<2048, 256, 0, stream>>>(x, attn_w, hb);
    // 2. convert QKV weights into one [3072][2048] bf16 Bt
    k_convT<<<dim3(32, 32), 256, 0, stream>>>(wq, Wqkv, 2048, 2048, 1, 0);
    k_convT<<<dim3(32, 8), 256, 0, stream>>>(wk, Wqkv + 4194304, 2048, 512, 1, 0);
    k_convT<<<dim3(32, 8), 256, 0, stream>>>(wv, Wqkv + 5242880, 2048, 512, 1, 0);
    // 3. fused QKV projection, split-K=2 -> bf16 partials
    k_gemm10<5><<<dim3(12, 8, 2), 512, LDS10, stream>>>(hb, Wqkv, pQ, nullptr,
                                                        2048, 3072, 2048, 1024);
    // 4. fused reduce + RoPE + qk-norm + scatter
    k_qkvrope<<<2048, 256, 0, stream>>>(pQ, qb, kb, vb);
    // 5. V transpose (vb[2048][512] -> vt[512][2048]); Wqkv dead now
    k_transpose<<<dim3(64, 16), 256, 0, stream>>>(vb, vt, 2048, 512);
    // 6. attention (complementary pairing, 2 blocks/CU)
    k_attn<<<dim3(32, 16), 256, LDSA, stream>>>(qb, kb, vt, ob);
    // 7. O projection, split-K=4 -> bf16 partials; fused reduce+rmsnorm
    k_convT<<<dim3(32, 32), 256, 0, stream>>>(wo, WoT, 2048, 2048, 1, 0);
    k_gemm10<5><<<dim3(8, 8, 4), 512, LDS10, stream>>>(ob, WoT, pO, nullptr,
                                                       2048, 2048, 2048, 512);
    k_reduce_rms<<<2048, 256, 0, stream>>>(pO, x, mlp_w, x2, hb, 4);
    // 8. convert gate (even rows) + up (odd rows) interleaved [16384][2048]
    k_convT<<<dim3(32, 128), 256, 0, stream>>>(wgate, Wgu, 2048, 8192, 2, 0);
    k_convT<<<dim3(32, 128), 256, 0, stream>>>(wup, Wgu, 2048, 8192, 2, 1);
    // 9. fused gate+up GEMM with in-register silu epilogue -> gb
    k_gemm10<4><<<dim3(64, 8, 1), 512, LDS10, stream>>>(hb, Wgu, gb, nullptr,
                                                        2048, 16384, 2048, 2048);
    // 10. down GEMM, split-K=4 -> bf16 partials; reduce + residual -> out
    k_convT<<<dim3(128, 32), 256, 0, stream>>>(wdown, WdT, 8192, 2048, 1, 0);
    k_gemm10<5><<<dim3(8, 8, 4), 512, LDS10, stream>>>(gb, WdT, pD, nullptr,
                                                       2048, 2048, 8192, 2048);
    k_reduce<<<2048, 256, 0, stream>>>(pD, x2, out, 4, n8);
}

// Round 14
// 437.618 us; speedup vs baseline: 1.0816x; 1.0583x over previous
//
#include <hip/hip_runtime.h>

typedef __bf16 bf16;
typedef __bf16 bf16x4 __attribute__((ext_vector_type(4)));
typedef __bf16 bf16x8 __attribute__((ext_vector_type(8)));
typedef float f32x4 __attribute__((ext_vector_type(4)));

#define GLP16(gp, lp) __builtin_amdgcn_global_load_lds( \
    (const __attribute__((address_space(1))) void*)(gp), \
    (__attribute__((address_space(3))) void*)(lp), 16, 0, 0)

__device__ __forceinline__ f32x4 mfma16(bf16x8 a, bf16x8 b, f32x4 c) {
    return __builtin_amdgcn_mfma_f32_16x16x32_bf16(a, b, c, 0, 0, 0);
}

// ---------------- RMSNorm: fp32 in -> bf16 out, row = 2048 ----------------
__global__ __launch_bounds__(256) void k_rmsnorm(const float* __restrict__ x,
        const float* __restrict__ w, bf16* __restrict__ out) {
    const int H = 2048;
    size_t row = blockIdx.x;
    const float* xr = x + row * H;
    int base = threadIdx.x * 8;
    float4 a = *(const float4*)(xr + base);
    float4 b = *(const float4*)(xr + base + 4);
    float ss = a.x*a.x + a.y*a.y + a.z*a.z + a.w*a.w
             + b.x*b.x + b.y*b.y + b.z*b.z + b.w*b.w;
#pragma unroll
    for (int m = 32; m > 0; m >>= 1) ss += __shfl_xor(ss, m);
    __shared__ float red[4];
    if ((threadIdx.x & 63) == 0) red[threadIdx.x >> 6] = ss;
    __syncthreads();
    float tot = red[0] + red[1] + red[2] + red[3];
    float rs = rsqrtf(tot * (1.0f / H) + 1e-5f);
    float4 wa = *(const float4*)(w + base);
    float4 wb = *(const float4*)(w + base + 4);
    bf16x8 ov;
    ov[0] = (bf16)(a.x * rs * wa.x); ov[1] = (bf16)(a.y * rs * wa.y);
    ov[2] = (bf16)(a.z * rs * wa.z); ov[3] = (bf16)(a.w * rs * wa.w);
    ov[4] = (bf16)(b.x * rs * wb.x); ov[5] = (bf16)(b.y * rs * wb.y);
    ov[6] = (bf16)(b.z * rs * wb.z); ov[7] = (bf16)(b.w * rs * wb.w);
    *(bf16x8*)(out + row * H + base) = ov;
}

// ------- convT v2: W (K x N fp32) -> Wt (N*rmul+roff rows, K bf16 cols) ---
__global__ __launch_bounds__(256) void k_convT(const float* __restrict__ W,
        bf16* __restrict__ Wt, int K, int N, int rmul, int roff) {
    __shared__ float t[64][65];
    int k0 = blockIdx.x * 64, n0 = blockIdx.y * 64;
    int tid = threadIdx.x;
#pragma unroll
    for (int it = 0; it < 4; it++) {
        int idx = it * 256 + tid;
        int r = idx >> 4, c = (idx & 15) * 4;
        float4 v = *(const float4*)(W + (size_t)(k0 + r) * N + n0 + c);
        t[r][c] = v.x; t[r][c + 1] = v.y; t[r][c + 2] = v.z; t[r][c + 3] = v.w;
    }
    __syncthreads();
#pragma unroll
    for (int it = 0; it < 4; it++) {
        int idx = it * 256 + tid;
        int n = idx >> 4, kc = (idx & 15) * 4;
        bf16x4 o;
#pragma unroll
        for (int j = 0; j < 4; j++) o[j] = (bf16)t[kc + j][n];
        *(bf16x4*)(Wt + ((size_t)(n0 + n) * rmul + roff) * K + k0 + kc) = o;
    }
}

// ------- bf16 transpose: in (R x C) -> out (C x R) ------------------------
__global__ __launch_bounds__(256) void k_transpose(const bf16* __restrict__ in,
        bf16* __restrict__ out, int R, int C) {
    __shared__ bf16 t[32][33];
    int r0 = blockIdx.x * 32, c0 = blockIdx.y * 32;
    int tx = threadIdx.x & 31, ty = threadIdx.x >> 5;
#pragma unroll
    for (int i = 0; i < 4; i++)
        t[ty + i * 8][tx] = in[(size_t)(r0 + ty + i * 8) * C + c0 + tx];
    __syncthreads();
#pragma unroll
    for (int i = 0; i < 4; i++)
        out[(size_t)(c0 + ty + i * 8) * R + r0 + tx] = t[tx][ty + i * 8];
}

// ---------------- GEMM v8: 2-phase K-tile (best measured engine) ----------
// BM=BN=256, BK=64, 8 waves (2M x 4N), per-wave 128x64. LDS 128KB.
// P1: rd A-lo(8) B0(4) B1(4) | issue ALL 8 GLPs for tile t+1 |
//     setprio mm(0,0) mm(0,1) | barrier
// P2: rd A-hi(8) (reuse a[]) | setprio mm(1,0) mm(1,1) |
//     vmcnt(0) free drain (issued ~1.7 phases earlier) | barrier
// EPI: 4 = fused gate/up silu (even cols = gate), 5 = bf16 partial (split-K)
template<int EPI>
__global__ __launch_bounds__(512, 2) void k_gemm8(const bf16* __restrict__ A,
        const bf16* __restrict__ Bt, void* __restrict__ outp,
        const void* __restrict__ aux, int M, int N, int K, int ksplit) {
    extern __shared__ char lds[];
    const int tid = threadIdx.x, wave = tid >> 6, lane = tid & 63;
    const int lr = lane & 15, kg = lane >> 4;
    const int wm = wave >> 2, wn = wave & 3;
    const int bn = blockIdx.x, bm = blockIdx.y, split = blockIdx.z;
    const int row0 = bm * 256, col0 = bn * 256;
    const int kbeg = split * ksplit;
    const int NT = ksplit >> 6;
    const size_t K2 = (size_t)K * 2;
    const int xorm = (lr & 7) << 4;

    size_t soff[2];
#pragma unroll
    for (int s = 0; s < 2; s++) {
        int d = s * 8192 + tid * 16;
        int rh = d >> 7, c = d & 127;
        soff[s] = (size_t)rh * K2 + (c ^ ((rh & 7) << 4));
    }
    const char* Ab = (const char*)A + ((size_t)row0 * K + kbeg) * 2;
    const char* Bb = (const char*)Bt + ((size_t)col0 * K + kbeg) * 2;

    auto stA = [&](int t, int mh) {
        const char* src = Ab + (size_t)(mh * 128) * K2 + (size_t)t * 128;
        char* dst = lds + (t & 1) * 32768 + mh * 16384 + wave * 1024;
        GLP16(src + soff[0], dst);
        GLP16(src + soff[1], dst + 8192);
    };
    auto stB = [&](int t, int nh) {
        const char* src = Bb + (size_t)(nh * 128) * K2 + (size_t)t * 128;
        char* dst = lds + 65536 + (t & 1) * 32768 + nh * 16384 + wave * 1024;
        GLP16(src + soff[0], dst);
        GLP16(src + soff[1], dst + 8192);
    };

    f32x4 acc[8][4];
#pragma unroll
    for (int m = 0; m < 8; m++)
#pragma unroll
        for (int n = 0; n < 4; n++) acc[m][n] = (f32x4){0, 0, 0, 0};

    bf16x8 a[8], c0[4], c1[4];
    auto rdA = [&](const char* base, int mh) {
#pragma unroll
        for (int mi = 0; mi < 4; mi++)
#pragma unroll
            for (int kk = 0; kk < 2; kk++) {
                int rh = wm * 64 + mi * 16 + lr;
                int c = (kk * 64 + kg * 16) ^ xorm;
                a[mi * 2 + kk] = *(const bf16x8*)(base + mh * 16384 + rh * 128 + c);
            }
    };
    auto rdB = [&](const char* base, int nh, bf16x8 (&b)[4]) {
#pragma unroll
        for (int nj = 0; nj < 2; nj++)
#pragma unroll
            for (int kk = 0; kk < 2; kk++) {
                int rh = wn * 32 + nj * 16 + lr;
                int c = (kk * 64 + kg * 16) ^ xorm;
                b[nj * 2 + kk] = *(const bf16x8*)(base + nh * 16384 + rh * 128 + c);
            }
    };
    auto mm = [&](int mh, int nh, bf16x8 (&b)[4]) {
#pragma unroll
        for (int mi = 0; mi < 4; mi++)
#pragma unroll
            for (int nj = 0; nj < 2; nj++)
#pragma unroll
                for (int kk = 0; kk < 2; kk++)
                    acc[mh * 4 + mi][nh * 2 + nj] =
                        mfma16(a[mi * 2 + kk], b[nj * 2 + kk],
                               acc[mh * 4 + mi][nh * 2 + nj]);
    };

#define PBAR do { asm volatile("" ::: "memory"); \
                  __builtin_amdgcn_s_barrier(); \
                  asm volatile("" ::: "memory"); } while (0)

    stA(0, 0); stA(0, 1); stB(0, 0); stB(0, 1);
    asm volatile("s_waitcnt vmcnt(0)" ::: "memory");
    PBAR;

    for (int t = 0; t < NT; ++t) {
        const char* Ac = lds + (t & 1) * 32768;
        const char* Bc = lds + 65536 + (t & 1) * 32768;
        const bool m1 = (t + 1 < NT);
        // ---- phase 1: lo-half MFMAs; issue all next-tile staging
        rdA(Ac, 0); rdB(Bc, 0, c0); rdB(Bc, 1, c1);
        if (m1) { stA(t + 1, 0); stA(t + 1, 1); stB(t + 1, 0); stB(t + 1, 1); }
        __builtin_amdgcn_s_setprio(1);
        mm(0, 0, c0); mm(0, 1, c1);
        __builtin_amdgcn_s_setprio(0);
        PBAR;
        // ---- phase 2: hi-half MFMAs; free drain of next-tile staging
        rdA(Ac, 1);
        __builtin_amdgcn_s_setprio(1);
        mm(1, 0, c0); mm(1, 1, c1);
        __builtin_amdgcn_s_setprio(0);
        if (m1) asm volatile("s_waitcnt vmcnt(0)" ::: "memory");
        PBAR;
    }
#undef PBAR

#pragma unroll
    for (int mi = 0; mi < 8; mi++)
#pragma unroll
        for (int ni = 0; ni < 4; ni++)
#pragma unroll
            for (int r = 0; r < 4; r++) {
                size_t row = row0 + (mi >> 2) * 128 + wm * 64 + (mi & 3) * 16 + kg * 4 + r;
                size_t col = col0 + (ni >> 1) * 128 + wn * 32 + (ni & 1) * 16 + lr;
                float vv = acc[mi][ni][r];
                if (EPI == 5) {
                    ((bf16*)outp)[(size_t)split * M * N + row * N + col] = (bf16)vv;
                } else {  // EPI == 4: fused gate/up + silu
                    float pv = __shfl_xor(vv, 1);
                    float g = (lane & 1) ? pv : vv;
                    float u = (lane & 1) ? vv : pv;
                    float sg = g / (1.0f + __expf(-g));
                    if (!(lane & 1))
                        ((bf16*)outp)[row * (size_t)(N >> 1) + (col >> 1)] =
                            (bf16)(sg * u);
                }
            }
}

// ---- reduce: out = resid + sum_s parts[s] (bf16 partials), 8 elems/thr ---
__global__ __launch_bounds__(256) void k_reduce(const bf16* __restrict__ parts,
        const float* __restrict__ resid, float* __restrict__ out,
        int ns, size_t n8) {
    size_t i = (size_t)blockIdx.x * 256 + threadIdx.x;
    if (i >= n8) return;
    size_t base = i * 8;
    float4 a = *(const float4*)(resid + base);
    float4 b = *(const float4*)(resid + base + 4);
    for (int s = 0; s < ns; s++) {
        bf16x8 p = *(const bf16x8*)(parts + (size_t)s * n8 * 8 + base);
        a.x += (float)p[0]; a.y += (float)p[1]; a.z += (float)p[2]; a.w += (float)p[3];
        b.x += (float)p[4]; b.y += (float)p[5]; b.z += (float)p[6]; b.w += (float)p[7];
    }
    *(float4*)(out + base) = a;
    *(float4*)(out + base + 4) = b;
}

// ---- fused: x2 = resid + sum parts(bf16); hb = rmsnorm(x2)*w -------------
__global__ __launch_bounds__(256) void k_reduce_rms(const bf16* __restrict__ parts,
        const float* __restrict__ resid, const float* __restrict__ w,
        float* __restrict__ x2, bf16* __restrict__ hb, int ns) {
    const int H = 2048;
    size_t row = blockIdx.x;
    int base = threadIdx.x * 8;
    const float* rr = resid + row * H + base;
    float4 a = *(const float4*)rr;
    float4 b = *(const float4*)(rr + 4);
    for (int s = 0; s < ns; s++) {
        bf16x8 p = *(const bf16x8*)(parts + (size_t)s * H * 2048 + row * H + base);
        a.x += (float)p[0]; a.y += (float)p[1]; a.z += (float)p[2]; a.w += (float)p[3];
        b.x += (float)p[4]; b.y += (float)p[5]; b.z += (float)p[6]; b.w += (float)p[7];
    }
    *(float4*)(x2 + row * H + base) = a;
    *(float4*)(x2 + row * H + base + 4) = b;
    float ss = a.x*a.x + a.y*a.y + a.z*a.z + a.w*a.w
             + b.x*b.x + b.y*b.y + b.z*b.z + b.w*b.w;
#pragma unroll
    for (int m = 32; m > 0; m >>= 1) ss += __shfl_xor(ss, m);
    __shared__ float red[4];
    if ((threadIdx.x & 63) == 0) red[threadIdx.x >> 6] = ss;
    __syncthreads();
    float tot = red[0] + red[1] + red[2] + red[3];
    float rs = rsqrtf(tot * (1.0f / H) + 1e-5f);
    float4 wa = *(const float4*)(w + base);
    float4 wb = *(const float4*)(w + base + 4);
    bf16x8 ov;
    ov[0] = (bf16)(a.x * rs * wa.x); ov[1] = (bf16)(a.y * rs * wa.y);
    ov[2] = (bf16)(a.z * rs * wa.z); ov[3] = (bf16)(a.w * rs * wa.w);
    ov[4] = (bf16)(b.x * rs * wb.x); ov[5] = (bf16)(b.y * rs * wb.y);
    ov[6] = (bf16)(b.z * rs * wb.z); ov[7] = (bf16)(b.w * rs * wb.w);
    *(bf16x8*)(hb + row * H + base) = ov;
}

// ---- fused QKV finisher: split-K reduce + RoPE + qk-norm + scatter -------
__global__ __launch_bounds__(256) void k_qkvrope(const bf16* __restrict__ parts,
        bf16* __restrict__ qb, bf16* __restrict__ kb, bf16* __restrict__ vb) {
    int s = blockIdx.x;
    int tid = threadIdx.x, wave = tid >> 6, lane = tid & 63;
    const bf16* p0 = parts + (size_t)s * 3072;
    const bf16* p1 = p0 + (size_t)2048 * 3072;
    float f = exp2f((float)lane * -0.2076205059304601f);  // 10000^(-lane/64)
    float sn, cs;
    sincosf((float)s * f, &sn, &cs);
#pragma unroll 1
    for (int pass = 0; pass < 5; pass++) {
        int h = pass * 4 + wave;
        int base = (h < 16) ? h * 128 : 2048 + (h - 16) * 128;
        int c1 = base + lane, c2 = c1 + 64;
        float x1 = (float)p0[c1] + (float)p1[c1];
        float x2 = (float)p0[c2] + (float)p1[c2];
        float o1 = x1 * cs - x2 * sn;
        float o2 = x2 * cs + x1 * sn;
        float ss = o1 * o1 + o2 * o2;
#pragma unroll
        for (int m = 32; m > 0; m >>= 1) ss += __shfl_xor(ss, m);
        float rs = rsqrtf(ss * (1.0f / 128.0f) + 1e-5f);
        bf16* dst = (h < 16) ? (qb + (size_t)s * 2048 + h * 128)
                             : (kb + (size_t)s * 512 + (h - 16) * 128);
        dst[lane] = (bf16)(o1 * rs);
        dst[lane + 64] = (bf16)(o2 * rs);
    }
    int c = 2560 + tid * 2;
    float v0 = (float)p0[c] + (float)p1[c];
    float v1 = (float)p0[c + 1] + (float)p1[c + 1];
    bf16* vd = vb + (size_t)s * 512 + tid * 2;
    vd[0] = (bf16)v0; vd[1] = (bf16)v1;
}

// ------------- flash attention, GQA 16q/4kv, causal, tanh softcap ---------
__global__ __launch_bounds__(256, 2) void k_attn(const bf16* __restrict__ qg,
        const bf16* __restrict__ kgl, const bf16* __restrict__ vtg,
        bf16* __restrict__ og) {
    extern __shared__ char alds[];
    int pi = blockIdx.x, h = blockIdx.y, kvh = h >> 2;
    int qt = (pi & 1) ? (31 - (pi >> 1)) : (pi >> 1);
    int nt = qt + 1;
    int tid = threadIdx.x, wave = tid >> 6, lane = tid & 63;
    int lr = lane & 15, kgrp = lane >> 4;

    int rowQ[4], colQ[4], rowV[4], colV[4];
#pragma unroll
    for (int j = 0; j < 4; j++) {
        int p = j * 4096 + wave * 1024 + lane * 16;
        int ps = p ^ (((p >> 8) & 7) << 4);
        rowQ[j] = ps >> 8; colQ[j] = ps & 255;
        int pv = p ^ (((p >> 7) & 7) << 4);
        rowV[j] = pv >> 7; colV[j] = pv & 127;
    }

    const float C1 = 0.08838834764831845f / 50.0f;  // 1/(50*sqrt(128))
    const float L2E50 = 72.13475204444817f;         // 50*log2(e)

#pragma unroll
    for (int j = 0; j < 4; j++)
        GLP16((const char*)qg + (size_t)(qt * 64 + rowQ[j]) * 4096 + h * 256 + colQ[j],
              alds + j * 4096 + wave * 1024);
    for (int t = 0; t < 2 && t < nt; t++) {
#pragma unroll
        for (int j = 0; j < 4; j++)
            GLP16((const char*)kgl + (size_t)(t * 64 + rowQ[j]) * 1024 + kvh * 256 + colQ[j],
                  alds + 16384 + t * 16384 + j * 4096 + wave * 1024);
#pragma unroll
        for (int j = 0; j < 4; j++)
            GLP16((const char*)vtg + (size_t)(kvh * 128 + rowV[j]) * 4096 + t * 128 + colV[j],
                  alds + 49152 + t * 16384 + j * 4096 + wave * 1024);
    }
    if (nt > 1) asm volatile("s_waitcnt vmcnt(8)" ::: "memory");
    else        asm volatile("s_waitcnt vmcnt(0)" ::: "memory");
    __builtin_amdgcn_s_barrier();

    bf16x8 qf[4];
#pragma unroll
    for (int c = 0; c < 4; c++) {
        int b = (wave * 16 + lr) * 256 + c * 64 + kgrp * 16;
        qf[c] = *(const bf16x8*)(alds + (b ^ (((b >> 8) & 7) << 4)));
    }
    __builtin_amdgcn_s_barrier();

    f32x4 accO[8];
#pragma unroll
    for (int n = 0; n < 8; n++) accO[n] = (f32x4){0, 0, 0, 0};
    float lsum[4] = {0, 0, 0, 0};
    int qrow = qt * 64 + wave * 16 + kgrp * 4;

    for (int kt = 0; kt < nt; kt++) {
        int buf = kt & 1;
        const char* Kb = alds + 16384 + buf * 16384;
        const char* Vb = alds + 49152 + buf * 16384;
        char* Pb = alds;
#pragma unroll
        for (int j = 0; j < 4; j++) {
            f32x4 s = {0, 0, 0, 0};
#pragma unroll
            for (int c = 0; c < 4; c++) {
                int b = (j * 16 + lr) * 256 + c * 64 + kgrp * 16;
                bf16x8 kf = *(const bf16x8*)(Kb + (b ^ (((b >> 8) & 7) << 4)));
                s = mfma16(qf[c], kf, s);
            }
            int key = kt * 64 + j * 16 + lr;
#pragma unroll
            for (int r = 0; r < 4; r++) {
                float y = s[r] * C1;
                float y2 = y * y;
                float u = fmaf(y2, 0.13333333f, -0.33333333f);
                u = fmaf(y2, u, 1.0f);
                float t5 = y * u;                       // tanh(y)
                float pe = fmaf(t5, L2E50, -L2E50);     // (50t-50)*log2e
                float pv = (key <= qrow + r) ? exp2f(pe) : 0.0f;
                lsum[r] += pv;
                int wb = (wave * 16 + kgrp * 4 + r) * 128 + (j * 16 + lr) * 2;
                *(bf16*)(Pb + (wb ^ (((wb >> 7) & 7) << 4))) = (bf16)pv;
            }
        }
        bf16x8 pf[2];
#pragma unroll
        for (int ks2 = 0; ks2 < 2; ks2++) {
            int b = (wave * 16 + lr) * 128 + ks2 * 64 + kgrp * 16;
            pf[ks2] = *(const bf16x8*)(Pb + (b ^ (((b >> 7) & 7) << 4)));
        }
#pragma unroll
        for (int n = 0; n < 8; n++)
#pragma unroll
            for (int ks2 = 0; ks2 < 2; ks2++) {
                int b = (n * 16 + lr) * 128 + ks2 * 64 + kgrp * 16;
                bf16x8 vf = *(const bf16x8*)(Vb + (b ^ (((b >> 7) & 7) << 4)));
                accO[n] = mfma16(pf[ks2], vf, accO[n]);
            }
        __builtin_amdgcn_s_barrier();
        bool more = (kt + 2 < nt);
        if (more) {
            int t = kt + 2;
#pragma unroll
            for (int j = 0; j < 4; j++)
                GLP16((const char*)kgl + (size_t)(t * 64 + rowQ[j]) * 1024 + kvh * 256 + colQ[j],
                      alds + 16384 + buf * 16384 + j * 4096 + wave * 1024);
#pragma unroll
            for (int j = 0; j < 4; j++)
                GLP16((const char*)vtg + (size_t)(kvh * 128 + rowV[j]) * 4096 + t * 128 + colV[j],
                      alds + 49152 + buf * 16384 + j * 4096 + wave * 1024);
        }
        if (kt + 1 < nt) {
            if (more) asm volatile("s_waitcnt vmcnt(8)" ::: "memory");
            else      asm volatile("s_waitcnt vmcnt(0)" ::: "memory");
            __builtin_amdgcn_s_barrier();
        }
    }
#pragma unroll
    for (int r = 0; r < 4; r++) {
        float t = lsum[r];
        t += __shfl_xor(t, 1); t += __shfl_xor(t, 2);
        t += __shfl_xor(t, 4); t += __shfl_xor(t, 8);
        lsum[r] = t;
    }
#pragma unroll
    for (int n = 0; n < 8; n++)
#pragma unroll
        for (int r = 0; r < 4; r++) {
            size_t row = qt * 64 + wave * 16 + kgrp * 4 + r;
            og[row * 2048 + h * 128 + n * 16 + lr] = (bf16)(accO[n][r] / lsum[r]);
        }
}

// --------------------------------------------------------------------------
extern "C" void kernel_launch(void* const* d_in, const int* in_sizes, int n_in,
                              void* d_out, int out_size, void* d_ws, size_t ws_size,
                              hipStream_t stream) {
    const float* x      = (const float*)d_in[0];
    const float* attn_w = (const float*)d_in[1];
    const float* mlp_w  = (const float*)d_in[2];
    const float* wq     = (const float*)d_in[3];
    const float* wk     = (const float*)d_in[4];
    const float* wv     = (const float*)d_in[5];
    const float* wo     = (const float*)d_in[6];
    const float* wgate  = (const float*)d_in[7];
    const float* wup    = (const float*)d_in[8];
    const float* wdown  = (const float*)d_in[9];
    float* out = (float*)d_out;
    char* ws = (char*)d_ws;

    const size_t MB = 1024 * 1024;
    // timeline-disjoint workspace map:
    bf16* Wqkv = (bf16*)(ws + 0);        // [0,12.6) step 2-3
    bf16* vt   = (bf16*)(ws + 0);        // [0,2)    step 4-6 (Wqkv dead)
    bf16* pO   = (bf16*)(ws + 0);        // [0,33.5) O partials split4 (vt dead)
    bf16* Wgu  = (bf16*)(ws + 0);        // [0,64)   interleaved gate/up (pO dead)
    bf16* pD   = (bf16*)(ws + 0);        // [0,33.5) down partials (Wgu dead)
    bf16* WoT  = (bf16*)(ws + 64 * MB);  // [64,72)  step 7
    bf16* WdT  = (bf16*)(ws + 64 * MB);  // [64,96)  step 10 (WoT dead)
    bf16* hb   = (bf16*)(ws + 96 * MB);  // 8MB
    bf16* qb   = (bf16*)(ws + 104 * MB); // 8MB
    bf16* kb   = (bf16*)(ws + 112 * MB); // 2MB
    bf16* vb   = (bf16*)(ws + 114 * MB); // 2MB
    bf16* ob   = (bf16*)(ws + 116 * MB); // 8MB
    float* x2  = (float*)(ws + 124 * MB);// 16MB
    bf16* gb   = (bf16*)(ws + 140 * MB); // 32MB silu(g)*u
    bf16* pQ   = (bf16*)(ws + 172 * MB); // [172,198) QKV partials (bf16)

    const int LDS8 = 131072;
    hipFuncSetAttribute((const void*)&k_gemm8<4>,
        hipFuncAttributeMaxDynamicSharedMemorySize, LDS8);
    hipFuncSetAttribute((const void*)&k_gemm8<5>,
        hipFuncAttributeMaxDynamicSharedMemorySize, LDS8);
    const int LDSA = 81920;
    hipFuncSetAttribute((const void*)&k_attn,
        hipFuncAttributeMaxDynamicSharedMemorySize, LDSA);

    const size_t n8 = (size_t)2048 * 2048 / 8;

    // 1. attn RMSNorm
    k_rmsnorm<<<2048, 256, 0, stream>>>(x, attn_w, hb);
    // 2. convert QKV weights into one [3072][2048] bf16 Bt
    k_convT<<<dim3(32, 32), 256, 0, stream>>>(wq, Wqkv, 2048, 2048, 1, 0);
    k_convT<<<dim3(32, 8), 256, 0, stream>>>(wk, Wqkv + 4194304, 2048, 512, 1, 0);
    k_convT<<<dim3(32, 8), 256, 0, stream>>>(wv, Wqkv + 5242880, 2048, 512, 1, 0);
    // 3. fused QKV projection, split-K=2 -> bf16 partials
    k_gemm8<5><<<dim3(12, 8, 2), 512, LDS8, stream>>>(hb, Wqkv, pQ, nullptr,
                                                      2048, 3072, 2048, 1024);
    // 4. fused reduce + RoPE + qk-norm + scatter
    k_qkvrope<<<2048, 256, 0, stream>>>(pQ, qb, kb, vb);
    // 5. V transpose (vb[2048][512] -> vt[512][2048]); Wqkv dead now
    k_transpose<<<dim3(64, 16), 256, 0, stream>>>(vb, vt, 2048, 512);
    // 6. attention (complementary pairing, 2 blocks/CU)
    k_attn<<<dim3(32, 16), 256, LDSA, stream>>>(qb, kb, vt, ob);
    // 7. O projection, split-K=4 -> bf16 partials; fused reduce+rmsnorm
    k_convT<<<dim3(32, 32), 256, 0, stream>>>(wo, WoT, 2048, 2048, 1, 0);
    k_gemm8<5><<<dim3(8, 8, 4), 512, LDS8, stream>>>(ob, WoT, pO, nullptr,
                                                     2048, 2048, 2048, 512);
    k_reduce_rms<<<2048, 256, 0, stream>>>(pO, x, mlp_w, x2, hb, 4);
    // 8. convert gate (even rows) + up (odd rows) interleaved [16384][2048]
    k_convT<<<dim3(32, 128), 256, 0, stream>>>(wgate, Wgu, 2048, 8192, 2, 0);
    k_convT<<<dim3(32, 128), 256, 0, stream>>>(wup, Wgu, 2048, 8192, 2, 1);
    // 9. fused gate+up GEMM with in-register silu epilogue -> gb
    k_gemm8<4><<<dim3(64, 8, 1), 512, LDS8, stream>>>(hb, Wgu, gb, nullptr,
                                                      2048, 16384, 2048, 2048);
    // 10. down GEMM, split-K=4 -> bf16 partials; reduce + residual -> out
    k_convT<<<dim3(128, 32), 256, 0, stream>>>(wdown, WdT, 8192, 2048, 1, 0);
    k_gemm8<5><<<dim3(8, 8, 4), 512, LDS8, stream>>>(gb, WdT, pD, nullptr,
                                                     2048, 2048, 8192, 2048);
    k_reduce<<<2048, 256, 0, stream>>>(pD, x2, out, 4, n8);
}